// Round 5
// baseline (364.235 us; speedup 1.0000x reference)
//
#include <hip/hip_runtime.h>
#include <cstdint>

typedef unsigned long long u64;

// fused popcount-accumulate: add(ctpop(x), y) -> v_bcnt_u32_b32 x, y
__device__ __forceinline__ int pc_acc(u64 a, u64 w, int acc) {
    u64 x = a ^ w;
    acc = __builtin_popcount((unsigned)x) + acc;
    acc = __builtin_popcount((unsigned)(x >> 32)) + acc;
    return acc;
}

// ---------------------------------------------------------------------------
// prep: zero padded maps (blocks [0,1024)) + pack all 5 binary weight tensors
// (blocks [1024,...)), COMPLEMENTED sign bits, TRANSPOSED layout:
//   wpT[oc * 9*Wi + tap*Wi + cw], bit i = !(w[tap][cw*64+i][oc] > 0)
// so each lane's weights are contiguous -> imm-offset loads in bconv.
// ---------------------------------------------------------------------------
__global__ __launch_bounds__(256) void prep_kernel(
        const float* __restrict__ w2, const float* __restrict__ w3,
        const float* __restrict__ w4, const float* __restrict__ w5,
        const float* __restrict__ w6,
        u64* __restrict__ wp2, u64* __restrict__ wp3, u64* __restrict__ wp4,
        u64* __restrict__ wp5, u64* __restrict__ wp6,
        u64* __restrict__ pz, int nz) {
    const int ZB = 1024;
    if (blockIdx.x < ZB) {
        int i = blockIdx.x * 256 + threadIdx.x;
        const int stride = ZB * 256;
        for (; i < nz; i += stride) pz[i] = 0;
        return;
    }
    int wid = ((blockIdx.x - ZB) * 256 + threadIdx.x) >> 6;
    int lane = threadIdx.x & 63;
    const float* w; u64* wp; int Wi, Cout, base;
    if      (wid <  2304) { w = w2; wp = wp2; Wi = 2; Cout = 128; base = 0; }
    else if (wid <  6912) { w = w3; wp = wp3; Wi = 2; Cout = 256; base = 2304; }
    else if (wid < 16128) { w = w4; wp = wp4; Wi = 4; Cout = 256; base = 6912; }
    else if (wid < 34560) { w = w5; wp = wp5; Wi = 4; Cout = 512; base = 16128; }
    else if (wid < 71424) { w = w6; wp = wp6; Wi = 8; Cout = 512; base = 34560; }
    else return;
    int id = wid - base;
    int oc = id % Cout;
    int tw = id / Cout;            // tap*Wi + cw
    int tap = tw / Wi, cw = tw % Wi;
    int Cin = Wi * 64;
    float v = w[((size_t)tap * Cin + cw * 64 + lane) * Cout + oc];
    u64 mask = __ballot(!(v > 0.0f));
    if (lane == 0) wp[(size_t)oc * (9 * Wi) + tap * Wi + cw] = mask;
}

// ---------------------------------------------------------------------------
// conv1 (float, 3->128) + b1 + relu + bn1 -> sign bits, written into the
// PADDED 34x34x2-word p1 map. Weights in VGPRs, 8 px/thread sliding window.
// Double accumulation: sign decisions feed 5 binary layers; must be exact.
// ---------------------------------------------------------------------------
__global__ __launch_bounds__(128) void conv1_pack_kernel(
        const float* __restrict__ x, const float* __restrict__ w1,
        const float* __restrict__ b1, const float* __restrict__ s1,
        const float* __restrict__ bb1, u64* __restrict__ p1) {
    const int t = threadIdx.x;
    const int oc = t;
    const int bx = blockIdx.x;
    const int xseg = (bx & 3) << 3;    // 0,8,16,24
    const int y = (bx >> 2) & 31;
    const int b = bx >> 7;

    double wreg[27];
    #pragma unroll
    for (int k = 0; k < 27; k++) wreg[k] = (double)w1[k * 128 + oc];
    const double b1v = (double)b1[oc];
    // h = relu(acc+b1)*s + bb > 0  <=>  (bb>0) || acc > -bb/s - b1   (s>0)
    const double tneg = -(double)bb1[oc] / (double)s1[oc];
    const bool always = tneg < 0.0;
    const double thr = tneg - b1v;

    double acc[8];
    #pragma unroll
    for (int i = 0; i < 8; i++) acc[i] = 0.0;

    #pragma unroll
    for (int ky = 0; ky < 3; ky++) {
        int iy = y - 1 + ky;
        if (iy < 0 || iy > 31) continue;
        #pragma unroll
        for (int col = 0; col < 10; col++) {
            int ix = xseg - 1 + col;
            if (ix < 0 || ix > 31) continue;
            const float* xp = x + ((b * 32 + iy) * 32 + ix) * 3;
            #pragma unroll
            for (int c = 0; c < 3; c++) {
                double xv = (double)xp[c];
                #pragma unroll
                for (int kx = 0; kx < 3; kx++) {
                    int px = col - kx;          // output pixel this tap feeds
                    if (px >= 0 && px < 8)
                        acc[px] += xv * wreg[(ky * 3 + kx) * 3 + c];
                }
            }
        }
    }
    #pragma unroll
    for (int px = 0; px < 8; px++) {
        bool bit = always || (acc[px] > thr);
        u64 m = __ballot(bit);
        if ((t & 63) == 0)
            p1[((size_t)(b * 34 + y + 1) * 34 + xseg + px + 1) * 2 + (t >> 6)] = m;
    }
}

// ---------------------------------------------------------------------------
// Binary conv v4: zero-padded maps; TRANSPOSED weights (per-lane contiguous,
// imm-offset loads); fused v_bcnt accumulate (4 VALU per 64-MAC unit);
// weights streamed in (3 taps x CH<=4 words) register chunks via a
// non-unrolled runtime loop (no spills at WI=8). One wave = Wg pre-pool cols
// x 64 oc. Padding: exact integer correction
//   d = 2*m + 2*S_oob - 64*WI*(9 + n_oob)
// with S_oob from per-tap weight popcounts accumulated chunk-by-chunk.
// ---------------------------------------------------------------------------
template<int WI, int H, int W, int COUT, bool POOL, int XS, bool BITOUT>
__global__ __launch_bounds__(256, 4) void bconv4_kernel(
        const u64* __restrict__ in, const u64* __restrict__ wp,
        const float* __restrict__ bns, const float* __restrict__ bnb,
        u64* __restrict__ outb, float* __restrict__ outf) {
    constexpr int ROWS = POOL ? 2 : 1;       // pre-pool rows per wave
    constexpr int Ho   = POOL ? H / 2 : H;
    constexpr int Wo   = POOL ? W / 2 : W;
    constexpr int WoW  = COUT >> 6;
    constexpr int Hp   = H + 2, Wp = W + 2;
    constexpr int Wg   = W / XS;             // pre-pool cols per wave
    constexpr int Wog  = Wo / XS;            // output cols per wave
    constexpr int CH   = (WI < 4) ? WI : 4;  // weight words resident per chunk
    constexpr int NC   = WI / CH;            // chunks per tap-row

    const int lane = threadIdx.x & 63;
    int wid = (blockIdx.x * blockDim.x + threadIdx.x) >> 6;
    wid = __builtin_amdgcn_readfirstlane(wid);   // SGPR -> scalar a-loads
    const int wordo = wid % WoW;
    int t = wid / WoW;
    const int xg = t % XS; t /= XS;
    const int oy = t % Ho;
    const int b  = t / Ho;
    if (b >= 128) return;
    const int oc = wordo * 64 + lane;
    const int c0 = xg * Wg;                  // first pre-pool col (abs)
    const int base = POOL ? oy * 2 : oy;     // first pre-pool row (abs)

    int m[ROWS][Wg];
    #pragma unroll
    for (int r = 0; r < ROWS; r++)
        #pragma unroll
        for (int c = 0; c < Wg; c++) m[r][c] = 0;

    int S_top = 0, S_bot = 0, S_lef = 0, S_rig = 0;
    int C_tl = 0, C_tr = 0, C_bl = 0, C_br = 0;

    const u64* wlane = wp + (size_t)oc * (9 * WI);   // per-lane contiguous
    const u64* inb = in + (((size_t)b * Hp + base) * Wp + c0) * WI;

    #pragma unroll 1
    for (int kc = 0; kc < 3 * NC; kc++) {
        const int ky = kc / NC;
        const int ch = kc % NC;
        const u64* wptr = wlane + ky * 3 * WI + ch * CH;
        u64 wk[3][CH];
        #pragma unroll
        for (int kx = 0; kx < 3; kx++)
            #pragma unroll
            for (int cw = 0; cw < CH; cw++)
                wk[kx][cw] = wptr[kx * WI + cw];     // imm offsets

        // original-weight popcounts for this chunk (stored is complemented)
        int pg[3];
        #pragma unroll
        for (int kx = 0; kx < 3; kx++) {
            int s = 0;
            #pragma unroll
            for (int cw = 0; cw < CH; cw++) s += (int)__popcll(wk[kx][cw]);
            pg[kx] = 64 * CH - s;
        }
        S_lef += pg[0]; S_rig += pg[2];
        if (ky == 0) { S_top += pg[0] + pg[1] + pg[2]; C_tl += pg[0]; C_tr += pg[2]; }
        if (ky == 2) { S_bot += pg[0] + pg[1] + pg[2]; C_bl += pg[0]; C_br += pg[2]; }

        #pragma unroll
        for (int r = 0; r < ROWS; r++) {
            const u64* inrow = inb + (size_t)(r + ky) * Wp * WI + ch * CH;
            #pragma unroll
            for (int c = 0; c < Wg + 2; c++) {
                u64 av[CH];
                #pragma unroll
                for (int cw = 0; cw < CH; cw++) av[cw] = inrow[(size_t)c * WI + cw];
                #pragma unroll
                for (int kx = 0; kx < 3; kx++) {
                    const int col = c - kx;
                    if (col < 0 || col >= Wg) continue;
                    int acc = m[r][col];
                    #pragma unroll
                    for (int cw = 0; cw < CH; cw++)
                        acc = pc_acc(av[cw], wk[kx][cw], acc);   // matches
                    m[r][col] = acc;
                }
            }
        }
    }

    // ---- epilogue: padding correction, relu+pool max, threshold ----
    const double sc = (double)bns[oc];
    const double bi = (double)bnb[oc];

    #pragma unroll
    for (int po = 0; po < Wog; po++) {
        int pmax = 0;                        // relu then max == max(0, d...)
        #pragma unroll
        for (int r = 0; r < ROWS; r++) {
            #pragma unroll
            for (int wx = 0; wx < (POOL ? 2 : 1); wx++) {
                const int lc = POOL ? po * 2 + wx : po;   // local pre-pool col
                const int pc = c0 + lc;                   // abs pre-pool col
                const int pr = base + r;                  // abs pre-pool row
                const int top = (pr == 0), bot = (pr == H - 1);
                const int lef = (pc == 0), rig = (pc == W - 1);
                int n_oob = 3 * (top + bot + lef + rig)
                          - (top & lef) - (top & rig) - (bot & lef) - (bot & rig);
                int S = top * S_top + bot * S_bot + lef * S_lef + rig * S_rig
                      - (top & lef) * C_tl - (top & rig) * C_tr
                      - (bot & lef) * C_bl - (bot & rig) * C_br;
                int d = 2 * m[r][lc] + 2 * S - 64 * WI * (9 + n_oob);
                pmax = d > pmax ? d : pmax;
            }
        }
        double h = (double)pmax * sc + bi;
        if constexpr (BITOUT) {
            u64 mask = __ballot(h > 0.0);
            if (lane == 0)
                outb[((size_t)(b * (Ho + 2) + oy + 1) * (Wo + 2) + xg * Wog + po + 1) * WoW + wordo] = mask;
        } else {
            outf[((size_t)(b * Ho + oy) * Wo + xg * Wog + po) * COUT + oc] = (float)h;
        }
    }
}

// ---------------------------------------------------------------------------
// Dense (512x10) + softmax. One wave per row (b,y,x). 2048 rows.
// ---------------------------------------------------------------------------
__global__ __launch_bounds__(256) void dense_softmax_kernel(
        const float* __restrict__ h6, const float* __restrict__ dw,
        const float* __restrict__ db, float* __restrict__ out) {
    int lane = threadIdx.x & 63;
    int r = (blockIdx.x * blockDim.x + threadIdx.x) >> 6;
    if (r >= 2048) return;
    const float* hr = h6 + (size_t)r * 512;
    float part[10];
    #pragma unroll
    for (int d = 0; d < 10; d++) part[d] = 0.f;
    #pragma unroll
    for (int k = 0; k < 8; k++) {
        int c = lane + 64 * k;
        float hv = hr[c];
        const float* dwr = dw + c * 10;
        #pragma unroll
        for (int d = 0; d < 10; d++) part[d] += hv * dwr[d];
    }
    #pragma unroll
    for (int off = 32; off >= 1; off >>= 1) {
        #pragma unroll
        for (int d = 0; d < 10; d++) part[d] += __shfl_down(part[d], off, 64);
    }
    if (lane == 0) {
        float logits[10];
        float mx = -1e30f;
        #pragma unroll
        for (int d = 0; d < 10; d++) { logits[d] = part[d] + db[d]; mx = fmaxf(mx, logits[d]); }
        float se = 0.f;
        #pragma unroll
        for (int d = 0; d < 10; d++) { logits[d] = expf(logits[d] - mx); se += logits[d]; }
        float inv = 1.f / se;
        #pragma unroll
        for (int d = 0; d < 10; d++) out[(size_t)r * 10 + d] = logits[d] * inv;
    }
}

// ---------------------------------------------------------------------------
extern "C" void kernel_launch(void* const* d_in, const int* in_sizes, int n_in,
                              void* d_out, int out_size, void* d_ws, size_t ws_size,
                              hipStream_t stream) {
    const float* x    = (const float*)d_in[0];
    const float* w1   = (const float*)d_in[1];
    const float* b1   = (const float*)d_in[2];
    const float* w2   = (const float*)d_in[3];
    const float* w3   = (const float*)d_in[4];
    const float* w4   = (const float*)d_in[5];
    const float* w5   = (const float*)d_in[6];
    const float* w6   = (const float*)d_in[7];
    const float* bn1s = (const float*)d_in[8];
    const float* bn1b = (const float*)d_in[9];
    const float* bn2s = (const float*)d_in[10];
    const float* bn2b = (const float*)d_in[11];
    const float* bn3s = (const float*)d_in[12];
    const float* bn3b = (const float*)d_in[13];
    const float* bn4s = (const float*)d_in[14];
    const float* bn4b = (const float*)d_in[15];
    const float* bn5s = (const float*)d_in[16];
    const float* bn5b = (const float*)d_in[17];
    const float* bn6s = (const float*)d_in[18];
    const float* bn6b = (const float*)d_in[19];
    const float* dw   = (const float*)d_in[20];
    const float* db   = (const float*)d_in[21];
    float* out = (float*)d_out;

    // workspace layout (u64 units); p1..p5 are zero-padded bit maps
    u64* ws  = (u64*)d_ws;
    u64* wp2 = ws;              // 9*2*128  = 2304
    u64* wp3 = wp2 + 2304;      // 9*2*256  = 4608
    u64* wp4 = wp3 + 4608;      // 9*4*256  = 9216
    u64* wp5 = wp4 + 9216;      // 9*4*512  = 18432
    u64* wp6 = wp5 + 18432;     // 9*8*512  = 36864
    u64* p1  = wp6 + 36864;     // 128*34*34*2 = 295936
    u64* p2  = p1 + 295936;     // 128*18*18*2 = 82944
    u64* p3  = p2 + 82944;      // 128*18*18*4 = 165888
    u64* p4  = p3 + 165888;     // 128*10*10*4 = 51200
    u64* p5  = p4 + 51200;      // 128*10*10*8 = 102400
    float* h6 = (float*)(p5 + 102400);  // 128*4*4*512 floats = 4 MB
    const int NPAD = 295936 + 82944 + 165888 + 51200 + 102400;  // 698368

    // prep: zero padded maps + pack all binary weights (transposed layout)
    // blocks: 1024 zero + ceil(71424 waves / 4 per block) = 1024 + 17856
    prep_kernel<<<1024 + 17856, 256, 0, stream>>>(
        w2, w3, w4, w5, w6, wp2, wp3, wp4, wp5, wp6, p1, NPAD);

    // conv1 + bn1 -> p1 (padded)
    conv1_pack_kernel<<<128*32*4, 128, 0, stream>>>(x, w1, b1, bn1s, bn1b, p1);

    // each binary layer: exactly 8192 waves = 2048 blocks of 256
    bconv4_kernel<2,32,32,128,true, 2,true ><<<2048, 256, 0, stream>>>(p1, wp2, bn2s, bn2b, p2, nullptr);
    bconv4_kernel<2,16,16,256,false,1,true ><<<2048, 256, 0, stream>>>(p2, wp3, bn3s, bn3b, p3, nullptr);
    bconv4_kernel<4,16,16,256,true, 2,true ><<<2048, 256, 0, stream>>>(p3, wp4, bn4s, bn4b, p4, nullptr);
    bconv4_kernel<4,8,8,512,false,1,true ><<<2048, 256, 0, stream>>>(p4, wp5, bn5s, bn5b, p5, nullptr);
    bconv4_kernel<8,8,8,512,true, 2,false><<<2048, 256, 0, stream>>>(p5, wp6, bn6s, bn6b, nullptr, h6);

    // dense + softmax : 2048 rows, one wave each
    dense_softmax_kernel<<<2048*64/256, 256, 0, stream>>>(h6, dw, db, out);
}